// Round 7
// baseline (115.462 us; speedup 1.0000x reference)
//
#include <hip/hip_runtime.h>
#include <hip/hip_bf16.h>

// Problem shapes
#define B_SZ 64
#define T_PTS 300
#define N_SEG 299        // number of segments
#define VM 34            // 17*2
#define NPATH (B_SZ*VM)  // 2176
#define SIGC 120         // 3+9+27+81
#define FAN1 4080        // 34*120
#define H1 512
#define NOUT 155
#define CHUNK 5          // segments per lane (64*5=320 >= 299)
#define KSPL 48          // gemm1 K-splits
#define KW 85            // k per wave (48*85 = 4080)
#define JPW 8            // gemm1 j-rows per wave

// ---------------------------------------------------------------------------
// Absorb one linear segment with increment d into state a1..a4.
// Horner-factored (segment signature = exp(d)): 189 VALU ops.
// ---------------------------------------------------------------------------
__device__ __forceinline__ void sig_append(float a1[3], float a2[9], float a3[27], float a4[81],
                                           float d0, float d1, float d2) {
  const float d[3] = {d0, d1, d2};

  // Level 4 (uses OLD a1,a2,a3)
  float Z[3], Y[9], X[27];
#pragma unroll
  for (int i = 0; i < 3; i++) Z[i] = fmaf(d[i], 1.0f / 24.0f, (1.0f / 6.0f) * a1[i]);
#pragma unroll
  for (int e = 0; e < 9; e++) Y[e] = fmaf(d[e % 3], Z[e / 3], 0.5f * a2[e]);
#pragma unroll
  for (int e = 0; e < 27; e++) X[e] = fmaf(d[e % 3], Y[e / 3], a3[e]);
#pragma unroll
  for (int e = 0; e < 81; e++) a4[e] = fmaf(d[e % 3], X[e / 3], a4[e]);

  // Level 3 (uses OLD a1,a2)
  float Z3[3], Y3[9];
#pragma unroll
  for (int i = 0; i < 3; i++) Z3[i] = fmaf(d[i], 1.0f / 6.0f, 0.5f * a1[i]);
#pragma unroll
  for (int e = 0; e < 9; e++) Y3[e] = fmaf(d[e % 3], Z3[e / 3], a2[e]);
#pragma unroll
  for (int e = 0; e < 27; e++) a3[e] = fmaf(d[e % 3], Y3[e / 3], a3[e]);

  // Level 2 (uses OLD a1)
  float Z2[3];
#pragma unroll
  for (int i = 0; i < 3; i++) Z2[i] = fmaf(d[i], 0.5f, a1[i]);
#pragma unroll
  for (int e = 0; e < 9; e++) a2[e] = fmaf(d[e % 3], Z2[e / 3], a2[e]);

#pragma unroll
  for (int i = 0; i < 3; i++) a1[i] += d[i];
}

// ---------------------------------------------------------------------------
// DPP row_shl:OFF cross-lane fetch (OFF in 1..15): lane i reads lane i+OFF
// within its 16-lane row; out-of-row lanes get 0 (= Chen identity).
// VERIFIED in R3/R5/R6. (shfl/permlane butterflies removed this round —
// replaced by the cooperative LDS tree below.)
// ---------------------------------------------------------------------------
template <int OFF>
__device__ __forceinline__ float lane_down(float x) {
  return __int_as_float(__builtin_amdgcn_update_dpp(
      0, __float_as_int(x), 0x100 + OFF /*row_shl:OFF*/, 0xF, 0xF, true));
}

// One row-local Chen-combine round: state <- state (x) fetched-state.
template <int OFF>
__device__ __forceinline__ void chen_round(float a1[3], float a2[9], float a3[27], float a4[81]) {
  float B1[3], B2[9], B3[27];
#pragma unroll
  for (int i = 0; i < 3; i++) B1[i] = lane_down<OFF>(a1[i]);
#pragma unroll
  for (int i = 0; i < 9; i++) B2[i] = lane_down<OFF>(a2[i]);
#pragma unroll
  for (int i = 0; i < 27; i++) B3[i] = lane_down<OFF>(a3[i]);

#pragma unroll
  for (int e = 0; e < 81; e++) {
    const float b4 = lane_down<OFF>(a4[e]);  // reads pre-update a4[e]
    float v = a4[e] + b4;
    v = fmaf(a3[e / 3], B1[e % 3], v);
    v = fmaf(a2[e / 9], B2[e % 9], v);
    v = fmaf(a1[e / 27], B3[e % 27], v);
    a4[e] = v;
  }
#pragma unroll
  for (int e = 0; e < 27; e++) {
    float v = a3[e] + B3[e];
    v = fmaf(a2[e / 3], B1[e % 3], v);
    v = fmaf(a1[e / 9], B2[e % 9], v);
    a3[e] = v;
  }
#pragma unroll
  for (int e = 0; e < 9; e++) a2[e] = fmaf(a1[e / 3], B1[e % 3], a2[e] + B2[e]);
#pragma unroll
  for (int i = 0; i < 3; i++) a1[i] += B1[i];
}

// ---------------------------------------------------------------------------
// Kernel 1: signatures, reading inp directly.
// One PATH per WAVE (2176 one-wave blocks). Phases:
//   1) 64 lanes x 5 Horner appends (each lane: segments [5L, 5L+5)).
//   2) Rounds 1,2,4,8: DPP row-local Kogge-Stone suffix scan -> row leaders
//      (lanes 0,16,32,48) hold the 4 quarter-path signatures S0..S3.
//   3) Cooperative LDS tree (REPLACES the old shfl rounds 16,32): leaders
//      write S0..S3 to LDS; all 64 lanes compute M1=S0*S1, M2=S2*S3
//      element-wise (lane owns elements 2L,2L+1; one Chen-product element =
//      A[g]+B[g] + <=3 cross terms via precomputed flat offsets); then
//      M=M1*M2 the same way, stored straight to St (2 stores/lane, no
//      lane-0 serial epilogue). ~280 issues replace ~1100 + 240 bpermutes.
// Flat signature layout (LDS rows and St): [0,3)=lvl1 [3,12)=lvl2
// [12,39)=lvl3 [39,120)=lvl4. Cross-term offsets for element g:
//   lvl2 e=g-3 : A1[e/3]*B1[e%3]            -> (e/3,       e%3)
//   lvl3 e=g-12: A2[e/3]*B1[e%3]            -> (3+e/3,     e%3)
//                A1[e/9]*B2[e%9]            -> (e/9,       3+e%9)
//   lvl4 e=g-39: A3[e/3]*B1[e%3]            -> (12+e/3,    e%3)
//                A2[e/9]*B2[e%9]            -> (3+e/9,     3+e%9)
//                A1[e/27]*B3[e%27]          -> (e/27,      12+e%27)
// Rows padded to 128 so idle lanes (g>=120) read in-bounds garbage; their
// masks are 0 and their outputs are never stored.
// First 512 blocks also zero their ht row (b1 folded into gemm2).
// ---------------------------------------------------------------------------
__global__ __launch_bounds__(64)
__attribute__((amdgpu_waves_per_eu(1)))
void sig_kernel(const float* __restrict__ inp, float* __restrict__ St,
                float* __restrict__ ht) {
  __shared__ float smem[6 * 128];  // S0..S3 | M1 | M2   (3 KB)
  const int lane = threadIdx.x & 63;
  const int p = blockIdx.x;         // 2176 paths
  if (p < H1) ht[(size_t)p * 64 + lane] = 0.0f;  // zero-init for gemm1 atomics

  const int b = p / VM;
  const int vm = p - b * VM;
  const int t0 = lane * CHUNK;

  // inp element ((b*3+c)*300 + t)*34 + vm; channel stride 10200, t stride 34.
  const float* base = inp + (size_t)b * 3 * T_PTS * VM + vm;

  int tv[CHUNK + 1];
#pragma unroll
  for (int s = 0; s <= CHUNK; s++) {
    const int t = t0 + s;
    tv[s] = t < N_SEG ? t : N_SEG;
  }

  float a1[3], a2[9], a3[27], a4[81];
#pragma unroll
  for (int i = 0; i < 3; i++) a1[i] = 0.f;
#pragma unroll
  for (int i = 0; i < 9; i++) a2[i] = 0.f;
#pragma unroll
  for (int i = 0; i < 27; i++) a3[i] = 0.f;
#pragma unroll
  for (int i = 0; i < 81; i++) a4[i] = 0.f;

  float x0 = base[0 * T_PTS * VM + tv[0] * VM];
  float x1 = base[1 * T_PTS * VM + tv[0] * VM];
  float x2 = base[2 * T_PTS * VM + tv[0] * VM];
#pragma unroll
  for (int s = 0; s < CHUNK; s++) {
    const float y0 = base[0 * T_PTS * VM + tv[s + 1] * VM];
    const float y1 = base[1 * T_PTS * VM + tv[s + 1] * VM];
    const float y2 = base[2 * T_PTS * VM + tv[s + 1] * VM];
    const bool valid = (t0 + s) < N_SEG;
    const float d0 = valid ? (y0 - x0) : 0.0f;
    const float d1 = valid ? (y1 - x1) : 0.0f;
    const float d2 = valid ? (y2 - x2) : 0.0f;
    sig_append(a1, a2, a3, a4, d0, d1, d2);
    x0 = y0; x1 = y1; x2 = y2;
  }

  // Row-local suffix Chen product (16-lane Kogge-Stone via DPP).
  chen_round<1>(a1, a2, a3, a4);
  chen_round<2>(a1, a2, a3, a4);
  chen_round<4>(a1, a2, a3, a4);
  chen_round<8>(a1, a2, a3, a4);

  // ---- Phase 3: cooperative LDS tree ----
  // Row leaders write their quarter-signatures (flat layout, static indices).
  if ((lane & 15) == 0) {
    float* s = smem + (lane >> 4) * 128;
#pragma unroll
    for (int i = 0; i < 3; i++) s[i] = a1[i];
#pragma unroll
    for (int i = 0; i < 9; i++) s[3 + i] = a2[i];
#pragma unroll
    for (int i = 0; i < 27; i++) s[12 + i] = a3[i];
#pragma unroll
    for (int i = 0; i < 81; i++) s[39 + i] = a4[i];
  }
  __syncthreads();

  // Per-lane output elements g0=2L, g1=2L+1; precompute cross-term offsets.
  int o1a[2], o1b[2], o2a[2], o2b[2], o3a[2], o3b[2];
  float m2[2], m3[2], m4[2];
#pragma unroll
  for (int q = 0; q < 2; q++) {
    const int g = 2 * lane + q;
    o1a[q] = o1b[q] = o2a[q] = o2b[q] = o3a[q] = o3b[q] = 0;
    m2[q] = m3[q] = m4[q] = 0.f;
    if (g >= 39 && g < 120) {
      const int e = g - 39;
      o1a[q] = 12 + e / 3;  o1b[q] = e % 3;       m2[q] = 1.f;
      o2a[q] = 3 + e / 9;   o2b[q] = 3 + e % 9;   m3[q] = 1.f;
      o3a[q] = e / 27;      o3b[q] = 12 + e % 27; m4[q] = 1.f;
    } else if (g >= 12 && g < 39) {
      const int e = g - 12;
      o1a[q] = 3 + e / 3;   o1b[q] = e % 3;       m2[q] = 1.f;
      o2a[q] = e / 9;       o2b[q] = 3 + e % 9;   m3[q] = 1.f;
    } else if (g >= 3 && g < 12) {
      const int e = g - 3;
      o1a[q] = e / 3;       o1b[q] = e % 3;       m2[q] = 1.f;
    }
  }
  const int g0 = 2 * lane, g1 = 2 * lane + 1;

#define CHEN_ELEM(Aoff, Boff, g, q, dstvar)                                       \
  do {                                                                            \
    float c_ = smem[(Aoff) + (g)] + smem[(Boff) + (g)];                           \
    c_ = fmaf(m2[q] * smem[(Aoff) + o1a[q]], smem[(Boff) + o1b[q]], c_);          \
    c_ = fmaf(m3[q] * smem[(Aoff) + o2a[q]], smem[(Boff) + o2b[q]], c_);          \
    c_ = fmaf(m4[q] * smem[(Aoff) + o3a[q]], smem[(Boff) + o3b[q]], c_);          \
    dstvar = c_;                                                                  \
  } while (0)

  // Level A: M1 = S0*S1 (rows 0,1 -> row 4), M2 = S2*S3 (rows 2,3 -> row 5).
  {
    float v0, v1, w0, w1;
    CHEN_ELEM(0 * 128, 1 * 128, g0, 0, v0);
    CHEN_ELEM(0 * 128, 1 * 128, g1, 1, v1);
    CHEN_ELEM(2 * 128, 3 * 128, g0, 0, w0);
    CHEN_ELEM(2 * 128, 3 * 128, g1, 1, w1);
    smem[4 * 128 + g0] = v0;
    smem[4 * 128 + g1] = v1;
    smem[5 * 128 + g0] = w0;
    smem[5 * 128 + g1] = w1;
  }
  __syncthreads();

  // Level B: M = M1*M2, stored straight to St[(vm*120+g)*64 + b].
  {
    float v0, v1;
    CHEN_ELEM(4 * 128, 5 * 128, g0, 0, v0);
    CHEN_ELEM(4 * 128, 5 * 128, g1, 1, v1);
    float* dst = St + (size_t)(vm * SIGC) * 64 + b;
    if (g0 < SIGC) dst[(size_t)g0 * 64] = v0;
    if (g1 < SIGC) dst[(size_t)g1 * 64] = v1;
  }
#undef CHEN_ELEM
}

// ---------------------------------------------------------------------------
// Kernel 2: ht[j][b] += sum_k St[k][b] * W1[j][k].  lane = b (M=64=wave).
// 3072 waves: 48 K-splits (85 k each) x 64 j-groups (8 j each). sv[85]
// register-resident (static indices); W1 rows are wave-uniform streams
// (scalar loads). 8 independent FMA chains. Coalesced atomicAdd epilogue
// onto the zero-initialized ht (48 adds/element, order-independent).
// ---------------------------------------------------------------------------
__global__ __launch_bounds__(256) void gemm1_kernel(const float* __restrict__ St,
                                                    const float* __restrict__ W1,
                                                    float* __restrict__ ht) {
  const int lane = threadIdx.x & 63;
  int wave_id = (blockIdx.x * 256 + threadIdx.x) >> 6;        // 0..3071
  wave_id = __builtin_amdgcn_readfirstlane(wave_id);          // force SGPR
  const int ks = wave_id >> 6;    // 0..47  (k-range of 85)
  const int jg = wave_id & 63;    // 0..63  (8 j's each)
  const int k0 = ks * KW;

  const float* stp = St + (size_t)k0 * 64 + lane;
  const float* w[JPW];
#pragma unroll
  for (int r = 0; r < JPW; r++) w[r] = W1 + (size_t)(jg * JPW + r) * FAN1 + k0;  // uniform -> s_load

  float sv[KW];
#pragma unroll
  for (int i = 0; i < KW; i++) sv[i] = stp[(size_t)i * 64];

  float acc[JPW];
#pragma unroll
  for (int r = 0; r < JPW; r++) acc[r] = 0.f;

#pragma unroll
  for (int i = 0; i < KW; i++) {
#pragma unroll
    for (int r = 0; r < JPW; r++) acc[r] = fmaf(sv[i], w[r][i], acc[r]);
  }

  float* hp = ht + (size_t)(jg * JPW) * 64 + lane;
#pragma unroll
  for (int r = 0; r < JPW; r++) atomicAdd(hp + r * 64, acc[r]);
}

// ---------------------------------------------------------------------------
// Kernel 3: out[b][j] = sum_k2 (ht[k2][b] + b1[k2]) * W2[j][k2] + b2[j].
// lane = b. Block = one j; 4 waves split k2 (128 each). The b1 fold is a
// second wave-uniform FMA chain in the same loop; red[w] = acc + accb so
// the LDS reduce also sums the b1·W2[j] correction. Single non-atomic store.
// ---------------------------------------------------------------------------
__global__ __launch_bounds__(256) void gemm2_kernel(const float* __restrict__ ht,
                                                    const float* __restrict__ W2,
                                                    const float* __restrict__ b1,
                                                    const float* __restrict__ b2,
                                                    float* __restrict__ out) {
  const int j = blockIdx.x;              // 0..154
  const int lane = threadIdx.x & 63;
  int w = threadIdx.x >> 6;              // 0..3
  w = __builtin_amdgcn_readfirstlane(w);
  __shared__ float red[4][64];

  const float* htp = ht + (size_t)(w * 128) * 64 + lane;
  const float* w2r = W2 + (size_t)j * H1 + w * 128;  // uniform -> s_load
  const float* b1r = b1 + w * 128;                   // uniform -> s_load
  float acc = 0.f, accb = 0.f;
#pragma unroll 8
  for (int k = 0; k < 128; k++) {
    const float wv = w2r[k];
    acc = fmaf(wv, htp[(size_t)k * 64], acc);
    accb = fmaf(wv, b1r[k], accb);
  }

  red[w][lane] = acc + accb;
  __syncthreads();
  if (threadIdx.x < 64) {
    const float tot = red[0][lane] + red[1][lane] + red[2][lane] + red[3][lane];
    out[(size_t)lane * NOUT + j] = tot + b2[j];
  }
}

// ---------------------------------------------------------------------------
extern "C" void kernel_launch(void* const* d_in, const int* in_sizes, int n_in,
                              void* d_out, int out_size, void* d_ws, size_t ws_size,
                              hipStream_t stream) {
  const float* inp = (const float*)d_in[0];  // (64,3,300,17,2)
  const float* W1  = (const float*)d_in[1];  // (512,4080)
  const float* b1  = (const float*)d_in[2];  // (512,)
  const float* W2  = (const float*)d_in[3];  // (155,512)
  const float* b2  = (const float*)d_in[4];  // (155,)
  float* out = (float*)d_out;                // (64,155)

  // ws layout (floats): St | ht   (~1.2 MB total)
  float* St = (float*)d_ws;                  // 4080*64
  float* ht = St + (size_t)FAN1 * 64;        // 512*64

  sig_kernel<<<NPATH, 64, 0, stream>>>(inp, St, ht);
  gemm1_kernel<<<KSPL * 64 / 4, 256, 0, stream>>>(St, W1, ht);
  gemm2_kernel<<<NOUT, 256, 0, stream>>>(ht, W2, b1, b2, out);
}